// Round 1
// baseline (833.819 us; speedup 1.0000x reference)
//
#include <hip/hip_runtime.h>

// MoE top-2 of 8 experts. B=4096 tokens, D=1024, H=4096.
// Pipeline: convert x->bf16 | fp64 gating+bucketing | prefix+loss |
//           grouped GEMM1 (gather, relu, bf16 out) | grouped GEMM2 (fp32 out) |
//           combine y = log(g1*exp(o1)+g2*exp(o2)).

typedef __attribute__((ext_vector_type(8))) short short8;
typedef __attribute__((ext_vector_type(4))) float f32x4;

#define B_TOK 4096
#define D_DIM 1024
#define H_DIM 4096
#define N_EXP 8

__device__ __forceinline__ unsigned short f2bf(float f) {
  unsigned int u = __float_as_uint(f);
  u += 0x7fffu + ((u >> 16) & 1u);      // round-to-nearest-even
  return (unsigned short)(u >> 16);
}

// ---------------- x -> bf16 ----------------
__global__ __launch_bounds__(256) void convert_x_kernel(const float* __restrict__ x,
                                                        unsigned short* __restrict__ xb) {
  const size_t i = ((size_t)blockIdx.x * 256 + threadIdx.x) * 4;
  float4 v = *(const float4*)(x + i);
  ushort4 r;
  r.x = f2bf(v.x); r.y = f2bf(v.y); r.z = f2bf(v.z); r.w = f2bf(v.w);
  *(ushort4*)(xb + i) = r;
}

// ---------------- gating: fp64 logits, top-2, bucket ----------------
__global__ __launch_bounds__(256) void gating_kernel(
    const float* __restrict__ x, const float* __restrict__ wg,
    int* __restrict__ counts, float* __restrict__ importance,
    int* __restrict__ bucket, int* __restrict__ tok_e,
    int* __restrict__ tok_p, float* __restrict__ tok_g) {
  const int lane = threadIdx.x & 63;
  const int t = blockIdx.x * 4 + (threadIdx.x >> 6);
  const float* xr = x + (size_t)t * D_DIM;
  double acc[8] = {0, 0, 0, 0, 0, 0, 0, 0};
  for (int d = lane; d < D_DIM; d += 64) {
    double xv = (double)xr[d];
    const float4 w0 = *(const float4*)(wg + d * 8);
    const float4 w1 = *(const float4*)(wg + d * 8 + 4);
    acc[0] += xv * (double)w0.x;
    acc[1] += xv * (double)w0.y;
    acc[2] += xv * (double)w0.z;
    acc[3] += xv * (double)w0.w;
    acc[4] += xv * (double)w1.x;
    acc[5] += xv * (double)w1.y;
    acc[6] += xv * (double)w1.z;
    acc[7] += xv * (double)w1.w;
  }
#pragma unroll
  for (int e = 0; e < 8; ++e) {
    double v = acc[e];
#pragma unroll
    for (int m = 32; m > 0; m >>= 1) v += __shfl_xor(v, m, 64);
    acc[e] = v;
  }
  if (lane == 0) {
    double b1v = -1e300, b2v = -1e300;
    int i1 = 0, i2 = 0;
#pragma unroll
    for (int e = 0; e < 8; ++e) {
      double v = acc[e];
      if (v > b1v) { b2v = b1v; i2 = i1; b1v = v; i1 = e; }
      else if (v > b2v) { b2v = v; i2 = e; }
    }
    // softmax over the two top logits (max-subtract, as jax.nn.softmax does)
    float ex = expf((float)b2v - (float)b1v);
    float den = 1.f + ex;
    float g1 = 1.f / den, g2 = ex / den;
    int p1 = atomicAdd(&counts[i1], 1);
    int p2 = atomicAdd(&counts[i2], 1);
    bucket[i1 * B_TOK + p1] = t;
    bucket[i2 * B_TOK + p2] = t;
    tok_e[2 * t] = i1; tok_e[2 * t + 1] = i2;
    tok_p[2 * t] = p1; tok_p[2 * t + 1] = p2;
    tok_g[2 * t] = g1; tok_g[2 * t + 1] = g2;
    atomicAdd(&importance[i1], g1);
    atomicAdd(&importance[i2], g2);
  }
}

// ---------------- prefix offsets + balancing loss ----------------
__global__ void finalize_kernel(const int* __restrict__ counts,
                                const float* __restrict__ importance,
                                const float* __restrict__ coef,
                                int* __restrict__ offs, float* __restrict__ loss_out) {
  if (threadIdx.x == 0 && blockIdx.x == 0) {
    int o = 0;
    for (int e = 0; e < 8; ++e) { offs[e] = o; o += counts[e]; }
    offs[8] = o;
    double mi = 0, ml = 0;
    for (int e = 0; e < 8; ++e) { mi += (double)importance[e]; ml += (double)counts[e]; }
    mi *= 0.125; ml *= 0.125;
    double vi = 0, vl = 0;
    for (int e = 0; e < 8; ++e) {
      double di = (double)importance[e] - mi; vi += di * di;
      double dl = (double)counts[e]    - ml; vl += dl * dl;
    }
    vi /= 7.0; vl /= 7.0;  // ddof=1
    double loss = (vi / (mi * mi + 1e-10) + vl / (ml * ml + 1e-10)) * (double)coef[0];
    *loss_out = (float)loss;
  }
}

// ---------------- grouped GEMM: 128x128 tile, BK=32, 16x16x32 bf16 MFMA ----------------
// A rows: gathered x tokens (GATHER) or contiguous h slots. W: fp32 [E][KDIM][NDIM],
// n-contiguous -> staged with fp32->bf16 convert + transpose into LDS [n][k].
template <int KDIM, int NDIM, bool GATHER, bool RELU, bool OUT_BF16>
__global__ __launch_bounds__(256) void grouped_ffn_gemm(
    const unsigned short* __restrict__ A, const float* __restrict__ W,
    const float* __restrict__ bias, const int* __restrict__ counts,
    const int* __restrict__ offs, const int* __restrict__ bucket,
    void* __restrict__ Out) {
  const int e = blockIdx.z;
  const int n_e = counts[e];
  const int row0 = blockIdx.y * 128;
  if (row0 >= n_e) return;
  const int m_cnt = min(128, n_e - row0);
  const int n0 = blockIdx.x * 128;
  const int slot0 = offs[e] + row0;

  __shared__ unsigned short Alds[128][40];  // rows 80 B -> conflict-free b128 reads
  __shared__ unsigned short Blds[128][40];  // [n][k], padded
  __shared__ int toklds[128];

  const int tid = threadIdx.x;
  const int lane = tid & 63;
  const int q = lane >> 4;
  const int l15 = lane & 15;
  const int wid = tid >> 6;
  const int wm = (wid >> 1) * 64;
  const int wn = (wid & 1) * 64;

  if (GATHER && tid < 128) {
    toklds[tid] = bucket[e * B_TOK + row0 + min(tid, m_cnt - 1)];
  }
  __syncthreads();

  // A staging: 512 16-B chunks; thread t -> chunks t and t+256
  const int ar0 = tid >> 2, ap0 = (tid & 3) * 8;
  const int ar1 = ar0 + 64;
  size_t arow0, arow1;
  if (GATHER) {
    arow0 = (size_t)toklds[ar0] * KDIM;
    arow1 = (size_t)toklds[ar1] * KDIM;
  } else {
    arow0 = (size_t)(slot0 + min(ar0, m_cnt - 1)) * KDIM;
    arow1 = (size_t)(slot0 + min(ar1, m_cnt - 1)) * KDIM;
  }

  // B staging: thread t -> column n = t&127, k-groups {bp0..bp0+7, bp0+16..bp0+23}
  const int bn = tid & 127;
  const int bp0 = (tid >> 7) * 8;  // 0 or 8
  const float* We = W + (size_t)e * KDIM * NDIM + n0;

  f32x4 acc[4][4] = {};

  for (int k0 = 0; k0 < KDIM; k0 += 32) {
    uint4 av0 = *(const uint4*)(A + arow0 + k0 + ap0);
    uint4 av1 = *(const uint4*)(A + arow1 + k0 + ap0);
    float bv0[8], bv1[8];
#pragma unroll
    for (int j = 0; j < 8; ++j) {
      bv0[j] = We[(size_t)(k0 + bp0 + j) * NDIM + bn];        // coalesced across lanes
      bv1[j] = We[(size_t)(k0 + bp0 + 16 + j) * NDIM + bn];
    }
    __syncthreads();  // previous iter's LDS reads done
    *(uint4*)&Alds[ar0][ap0] = av0;
    *(uint4*)&Alds[ar1][ap0] = av1;
    union { unsigned short s[8]; uint4 v; } p0, p1;
#pragma unroll
    for (int j = 0; j < 8; ++j) { p0.s[j] = f2bf(bv0[j]); p1.s[j] = f2bf(bv1[j]); }
    *(uint4*)&Blds[bn][bp0] = p0.v;
    *(uint4*)&Blds[bn][bp0 + 16] = p1.v;
    __syncthreads();

    short8 af[4], bf[4];
#pragma unroll
    for (int mi = 0; mi < 4; ++mi) af[mi] = *(const short8*)&Alds[wm + mi * 16 + l15][q * 8];
#pragma unroll
    for (int ni = 0; ni < 4; ++ni) bf[ni] = *(const short8*)&Blds[wn + ni * 16 + l15][q * 8];
#pragma unroll
    for (int mi = 0; mi < 4; ++mi)
#pragma unroll
      for (int ni = 0; ni < 4; ++ni)
        acc[mi][ni] = __builtin_amdgcn_mfma_f32_16x16x32_bf16(af[mi], bf[ni], acc[mi][ni], 0, 0, 0);
  }

  // epilogue: C/D layout col=lane&15, row=(lane>>4)*4+reg  [m89-verified]
  const float* be = bias + (size_t)e * NDIM + n0;
#pragma unroll
  for (int ni = 0; ni < 4; ++ni) {
    const int c = wn + ni * 16 + l15;
    const float bvv = be[c];
#pragma unroll
    for (int mi = 0; mi < 4; ++mi) {
      const int rb = wm + mi * 16 + q * 4;
#pragma unroll
      for (int rg = 0; rg < 4; ++rg) {
        const int r = rb + rg;
        if (r < m_cnt) {
          float v = acc[mi][ni][rg] + bvv;
          if (RELU) v = fmaxf(v, 0.f);
          if (OUT_BF16)
            ((unsigned short*)Out)[(size_t)(slot0 + r) * NDIM + n0 + c] = f2bf(v);
          else
            ((float*)Out)[(size_t)(slot0 + r) * NDIM + n0 + c] = v;
        }
      }
    }
  }
}

// ---------------- combine ----------------
__device__ __forceinline__ float comb1(float a, float b, float g1, float g2) {
  float c = g1 * expf(a) + g2 * expf(b);
  if (c == 0.f) c = 2.220446049250313e-16f;  // EPS, as in reference
  return logf(c);
}

__global__ __launch_bounds__(256) void combine_kernel(
    const float* __restrict__ o_buf, const int* __restrict__ offs,
    const int* __restrict__ tok_e, const int* __restrict__ tok_p,
    const float* __restrict__ tok_g, float* __restrict__ y) {
  const int t = blockIdx.x;
  const int e1 = tok_e[2 * t], e2 = tok_e[2 * t + 1];
  const int s1 = offs[e1] + tok_p[2 * t];
  const int s2 = offs[e2] + tok_p[2 * t + 1];
  const float g1 = tok_g[2 * t], g2 = tok_g[2 * t + 1];
  const float4* o1 = (const float4*)(o_buf + (size_t)s1 * D_DIM);
  const float4* o2 = (const float4*)(o_buf + (size_t)s2 * D_DIM);
  float4* yr = (float4*)(y + (size_t)t * D_DIM);
  const int i = threadIdx.x;  // 256 threads x float4 = 1024 cols
  float4 a = o1[i], b = o2[i];
  float4 r;
  r.x = comb1(a.x, b.x, g1, g2);
  r.y = comb1(a.y, b.y, g1, g2);
  r.z = comb1(a.z, b.z, g1, g2);
  r.w = comb1(a.w, b.w, g1, g2);
  yr[i] = r;
}

// ---------------- launch ----------------
extern "C" void kernel_launch(void* const* d_in, const int* in_sizes, int n_in,
                              void* d_out, int out_size, void* d_ws, size_t ws_size,
                              hipStream_t stream) {
  const float* x  = (const float*)d_in[0];
  const float* wg = (const float*)d_in[1];
  const float* W1 = (const float*)d_in[2];
  const float* b1 = (const float*)d_in[3];
  const float* W2 = (const float*)d_in[4];
  const float* b2 = (const float*)d_in[5];
  const float* cf = (const float*)d_in[6];
  float* y = (float*)d_out;

  char* w = (char*)d_ws;
  unsigned short* x_bf = (unsigned short*)(w);              // 8,388,608 B
  int*   counts = (int*)(w + 8388608);                      // 32 B
  float* imp    = (float*)(w + 8388640);                    // 32 B
  int*   offs   = (int*)(w + 8388672);                      // 9 ints (pad 64)
  int*   tok_e  = (int*)(w + 8388736);                      // 32768 B
  int*   tok_p  = (int*)(w + 8421504);                      // 32768 B
  float* tok_g  = (float*)(w + 8454272);                    // 32768 B
  int*   bucket = (int*)(w + 8487040);                      // 131072 B
  unsigned short* h_buf = (unsigned short*)(w + 8618112);   // 67,108,864 B
  float* o_buf  = (float*)(w + 75726976);                   // 33,554,432 B
  if (ws_size < 109281408) return;  // need ~104 MiB of scratch

  hipMemsetAsync(counts, 0, 64, stream);  // counts + importance

  convert_x_kernel<<<4096, 256, 0, stream>>>(x, x_bf);
  gating_kernel<<<1024, 256, 0, stream>>>(x, wg, counts, imp, bucket, tok_e, tok_p, tok_g);
  finalize_kernel<<<1, 64, 0, stream>>>(counts, imp, cf, offs, y + (size_t)B_TOK * D_DIM);
  grouped_ffn_gemm<D_DIM, H_DIM, true, true, true>
      <<<dim3(H_DIM / 128, B_TOK / 128, N_EXP), 256, 0, stream>>>(
          x_bf, W1, b1, counts, offs, bucket, (void*)h_buf);
  grouped_ffn_gemm<H_DIM, D_DIM, false, false, false>
      <<<dim3(D_DIM / 128, B_TOK / 128, N_EXP), 256, 0, stream>>>(
          h_buf, W2, b2, counts, offs, bucket, (void*)o_buf);
  combine_kernel<<<4096, 256, 0, stream>>>(o_buf, offs, tok_e, tok_p, tok_g, y);
}